// Round 3
// baseline (348.070 us; speedup 1.0000x reference)
//
#include <hip/hip_runtime.h>

#define M_TOK 16384          // B*T
#define D_DIM 768
#define K_CB  2048

#define BTOK  128            // token tile
#define BCODE 128            // code tile
#define BK    32             // K chunk (one mfma k=32)
#define KSPLIT 8
#define SLICE (K_CB / KSPLIT)   // 256 codes per block
#define NCT   (SLICE / BCODE)   // 2 code tiles per block
#define NSLOT (KSPLIT * 2)      // 16 per-token top2 slots (slice x code-half)
#define EPS   0.25f             // rescore margin (3-pass err ~1e-3; huge margin)

typedef __attribute__((ext_vector_type(8))) short bf16x8;
typedef __attribute__((ext_vector_type(4))) float f32x4;

__device__ __forceinline__ unsigned short f2bf(float x) {   // RNE f32->bf16
    unsigned u = __float_as_uint(x);
    return (unsigned short)((u + 0x7fffu + ((u >> 16) & 1u)) >> 16);
}
__device__ __forceinline__ float bf2f(unsigned short h) {
    return __uint_as_float((unsigned)h << 16);
}

#define ASYNC16(gp, lp) __builtin_amdgcn_global_load_lds( \
    (const __attribute__((address_space(1))) void*)(gp),  \
    (__attribute__((address_space(3))) void*)(lp), 16, 0, 0)

// ---------------------------------------------------------------------------
// Prep A: codebook f32 -> hi/lo bf16 planes + e_sq. One wave per code row.
// ---------------------------------------------------------------------------
__global__ void vq_prep_cb(const float* __restrict__ cb,
                           unsigned short* __restrict__ cb_hi,
                           unsigned short* __restrict__ cb_lo,
                           float* __restrict__ esq) {
    const int w = threadIdx.x >> 6, lane = threadIdx.x & 63;
    const int k = blockIdx.x * 4 + w;
    const float* row = cb + (size_t)k * D_DIM;
    unsigned short* hk = cb_hi + (size_t)k * D_DIM;
    unsigned short* lk = cb_lo + (size_t)k * D_DIM;
    float s = 0.f;
    for (int j = lane; j < D_DIM; j += 64) {
        float x = row[j];
        s = fmaf(x, x, s);
        unsigned short h = f2bf(x);
        hk[j] = h;
        lk[j] = f2bf(x - bf2f(h));
    }
    #pragma unroll
    for (int off = 32; off; off >>= 1) s += __shfl_down(s, off);
    if (!lane) esq[k] = s;
}

// ---------------------------------------------------------------------------
// Prep B: tokens f32 -> hi/lo bf16 planes (into d_out scratch). 8 floats/thr.
// ---------------------------------------------------------------------------
__global__ void vq_prep_tok(const float* __restrict__ tok,
                            unsigned short* __restrict__ th,
                            unsigned short* __restrict__ tl) {
    const int N8 = (M_TOK * D_DIM) / 8;
    const int stride = gridDim.x * blockDim.x;
    for (int i = blockIdx.x * blockDim.x + threadIdx.x; i < N8; i += stride) {
        const float4 a = *(const float4*)(tok + (size_t)i * 8);
        const float4 b = *(const float4*)(tok + (size_t)i * 8 + 4);
        const float v[8] = {a.x, a.y, a.z, a.w, b.x, b.y, b.z, b.w};
        unsigned hh[8], ll[8];
        #pragma unroll
        for (int j = 0; j < 8; ++j) {
            const unsigned short h = f2bf(v[j]);
            hh[j] = h;
            ll[j] = f2bf(v[j] - bf2f(h));
        }
        uint4 ph, pl;
        ph.x = hh[0] | (hh[1] << 16);  ph.y = hh[2] | (hh[3] << 16);
        ph.z = hh[4] | (hh[5] << 16);  ph.w = hh[6] | (hh[7] << 16);
        pl.x = ll[0] | (ll[1] << 16);  pl.y = ll[2] | (ll[3] << 16);
        pl.z = ll[4] | (ll[5] << 16);  pl.w = ll[6] | (ll[7] << 16);
        *(uint4*)(th + (size_t)i * 8) = ph;
        *(uint4*)(tl + (size_t)i * 8) = pl;
    }
}

// ---------------------------------------------------------------------------
// MFMA distance kernel. 4 waves (2 code-halves x 2 token-halves), pure bf16.
// All 4 tiles staged via global_load_lds; XOR-swizzled LDS layout:
//   slot h of row r lives at granule (h ^ ((r>>1)&3)) -> consecutive 8 lanes
//   cover all 8 bank-granules on ds_read_b128 (conflict-free minimum).
// Swizzle applied on the GLOBAL source address (LDS dest stays lane-linear).
// ---------------------------------------------------------------------------
__launch_bounds__(256, 4)
__global__ void vq_dist_mfma(const unsigned short* __restrict__ tok_hi,
                             const unsigned short* __restrict__ tok_lo,
                             const unsigned short* __restrict__ cb_hi,
                             const unsigned short* __restrict__ cb_lo,
                             const float* __restrict__ esq,
                             float4* __restrict__ top2) {
    __shared__ unsigned short sAh[BCODE * BK];
    __shared__ unsigned short sAl[BCODE * BK];
    __shared__ unsigned short sBh[BTOK * BK];
    __shared__ unsigned short sBl[BTOK * BK];
    __shared__ float esq_s[SLICE];

    const int tid  = threadIdx.x;
    const int lane = tid & 63;
    const int w    = tid >> 6;

    // XCD-bijective swizzle: all 128 blocks on one XCD share kslice -> the
    // 0.8MB codebook slice is L2-resident per XCD.
    const int bid = blockIdx.x;
    const int ksl = bid & 7;
    const int txi = bid >> 3;
    const int tokBase    = txi * BTOK;
    const int kSliceBase = ksl * SLICE;

    for (int j = tid; j < SLICE; j += 256) esq_s[j] = esq[kSliceBase + j];

    // staging: thread handles 2 granules/tile; LDS dest lane-linear,
    // global source pre-swizzled.
    int gOff[2], gLds[2];
    #pragma unroll
    for (int q = 0; q < 2; ++q) {
        const int G   = w * 128 + q * 64 + lane;
        const int row = G >> 2;
        const int hs  = (G & 3) ^ ((row >> 1) & 3);
        gOff[q] = (row * D_DIM + hs * 8) * 2;   // byte offset within plane tile
        gLds[q] = G * 16;
    }

    // frag read byte-offsets (dc-independent), same XOR on the read side
    const int h  = lane >> 4;
    const int lm = lane & 15;
    const int wc = (w >> 1) * 64;    // wave code offset
    const int wt = (w & 1) * 64;     // wave token offset
    int offA[4], offB[4];
    #pragma unroll
    for (int i = 0; i < 4; ++i) {
        const int rA = wc + i * 16 + lm;
        offA[i] = rA * 64 + ((h ^ ((rA >> 1) & 3)) * 16);
        const int rB = wt + i * 16 + lm;
        offB[i] = rB * 64 + ((h ^ ((rB >> 1) & 3)) * 16);
    }

    float rm1[4], rm2[4];
    int   rk1[4], rk2[4];
    #pragma unroll
    for (int j = 0; j < 4; ++j) {
        rm1[j] = 3.4e38f; rm2[j] = 3.4e38f;
        rk1[j] = 0x7fffffff; rk2[j] = 0x7fffffff;
    }

    const char* pBh = (const char*)(tok_hi + (size_t)tokBase * D_DIM);
    const char* pBl = (const char*)(tok_lo + (size_t)tokBase * D_DIM);

    for (int ct = 0; ct < NCT; ++ct) {
        const int codeBase = kSliceBase + ct * BCODE;
        const char* pAh = (const char*)(cb_hi + (size_t)codeBase * D_DIM);
        const char* pAl = (const char*)(cb_lo + (size_t)codeBase * D_DIM);

        f32x4 acc[4][4];
        #pragma unroll
        for (int i = 0; i < 4; ++i)
            #pragma unroll
            for (int j = 0; j < 4; ++j) acc[i][j] = (f32x4){0.f, 0.f, 0.f, 0.f};

        for (int dc = 0; dc < D_DIM; dc += BK) {
            const int dcb = dc * 2;
            __syncthreads();
            #pragma unroll
            for (int q = 0; q < 2; ++q) {
                ASYNC16(pAh + gOff[q] + dcb, (char*)sAh + gLds[q]);
                ASYNC16(pAl + gOff[q] + dcb, (char*)sAl + gLds[q]);
                ASYNC16(pBh + gOff[q] + dcb, (char*)sBh + gLds[q]);
                ASYNC16(pBl + gOff[q] + dcb, (char*)sBl + gLds[q]);
            }
            __syncthreads();   // drains vmcnt (global_load_lds) before reads

            bf16x8 ah[4], al[4], bh[4], bl[4];
            #pragma unroll
            for (int i = 0; i < 4; ++i) {
                ah[i] = *(const bf16x8*)((const char*)sAh + offA[i]);
                al[i] = *(const bf16x8*)((const char*)sAl + offA[i]);
            }
            #pragma unroll
            for (int j = 0; j < 4; ++j) {
                bh[j] = *(const bf16x8*)((const char*)sBh + offB[j]);
                bl[j] = *(const bf16x8*)((const char*)sBl + offB[j]);
            }
            #pragma unroll
            for (int i = 0; i < 4; ++i)
                #pragma unroll
                for (int j = 0; j < 4; ++j) {
                    acc[i][j] = __builtin_amdgcn_mfma_f32_16x16x32_bf16(ah[i], bh[j], acc[i][j], 0, 0, 0);
                    acc[i][j] = __builtin_amdgcn_mfma_f32_16x16x32_bf16(ah[i], bl[j], acc[i][j], 0, 0, 0);
                    acc[i][j] = __builtin_amdgcn_mfma_f32_16x16x32_bf16(al[i], bh[j], acc[i][j], 0, 0, 0);
                }
        }

        // fold tile into running top2 (ascending k preserves first-occurrence)
        #pragma unroll
        for (int j = 0; j < 4; ++j)
            #pragma unroll
            for (int i = 0; i < 4; ++i)
                #pragma unroll
                for (int r = 0; r < 4; ++r) {
                    const int cl = ct * BCODE + wc + i * 16 + (lane >> 4) * 4 + r;
                    const float s = esq_s[cl] - 2.0f * acc[i][j][r];
                    const int kg = kSliceBase + cl;
                    if (s < rm1[j]) {
                        rm2[j] = rm1[j]; rk2[j] = rk1[j];
                        rm1[j] = s;      rk1[j] = kg;
                    } else if (s < rm2[j]) {
                        rm2[j] = s; rk2[j] = kg;
                    }
                }
    }

    // cross-lane top2 merge over the 4 k-groups (xor 16, 32), then write
    #pragma unroll
    for (int j = 0; j < 4; ++j) {
        float m1 = rm1[j], m2 = rm2[j];
        int   k1 = rk1[j], k2 = rk2[j];
        #pragma unroll
        for (int off = 16; off <= 32; off <<= 1) {
            const float om1 = __shfl_xor(m1, off); const int ok1 = __shfl_xor(k1, off);
            const float om2 = __shfl_xor(m2, off); const int ok2 = __shfl_xor(k2, off);
            const bool aB = (m1 < om1) || (m1 == om1 && k1 < ok1);
            float n1m, n2m; int n1k, n2k;
            if (aB) {
                n1m = m1; n1k = k1;
                const bool t = (om1 < m2) || (om1 == m2 && ok1 < k2);
                n2m = t ? om1 : m2; n2k = t ? ok1 : k2;
            } else {
                n1m = om1; n1k = ok1;
                const bool t = (m1 < om2) || (m1 == om2 && k1 < ok2);
                n2m = t ? m1 : om2; n2k = t ? k1 : ok2;
            }
            m1 = n1m; k1 = n1k; m2 = n2m; k2 = n2k;
        }
        if (lane < 16) {
            const int t = tokBase + wt + j * 16 + lane;
            const int slot = ksl * 2 + (w >> 1);
            top2[(size_t)t * NSLOT + slot] =
                make_float4(m1, __int_as_float(k1), m2, __int_as_float(k2));
        }
    }
}

// ---------------------------------------------------------------------------
// Final (fused rescore+gather): one wave per token. Merge 16 top2 slots,
// exact fp32 rescore when gap <= EPS, gather row, indices, commit loss.
// ---------------------------------------------------------------------------
__global__ void vq_final(const float* __restrict__ token,
                         const float* __restrict__ cb,
                         const float* __restrict__ esq,
                         const float4* __restrict__ top2,
                         float* __restrict__ out_q,
                         float* __restrict__ out_idx,
                         float* __restrict__ out_loss) {
    const int w = threadIdx.x >> 6, lane = threadIdx.x & 63;
    const int t = blockIdx.x * 4 + w;

    // lane-parallel slot load (each slot 4x duplicated), butterfly merge
    const float4 sv = top2[(size_t)t * NSLOT + (lane & 15)];
    float m1 = sv.x, m2 = sv.z;
    int   k1 = __float_as_int(sv.y), k2 = __float_as_int(sv.w);
    #pragma unroll
    for (int off = 1; off <= 8; off <<= 1) {
        const float om1 = __shfl_xor(m1, off); const int ok1 = __shfl_xor(k1, off);
        const float om2 = __shfl_xor(m2, off); const int ok2 = __shfl_xor(k2, off);
        const bool aB = (m1 < om1) || (m1 == om1 && k1 < ok1);
        float n1m, n2m; int n1k, n2k;
        if (aB) {
            n1m = m1; n1k = k1;
            const bool c = (om1 < m2) || (om1 == m2 && ok1 < k2);
            n2m = c ? om1 : m2; n2k = c ? ok1 : k2;
        } else {
            n1m = om1; n1k = ok1;
            const bool c = (m1 < om2) || (m1 == om2 && k1 < ok2);
            n2m = c ? m1 : om2; n2k = c ? k1 : ok2;
        }
        m1 = n1m; k1 = n1k; m2 = n2m; k2 = n2k;
    }

    unsigned choice = (unsigned)k1;
    if (!(m2 - m1 > EPS)) {
        // exact fp32 rescore of both candidates (wave-uniform branch)
        const float* tr = token + (size_t)t * D_DIM;
        const float* c1 = cb + (size_t)k1 * D_DIM;
        const float* c2 = cb + (size_t)k2 * D_DIM;
        float d1 = 0.f, d2 = 0.f;
        for (int e = lane; e < D_DIM; e += 64) {
            const float x = tr[e];
            d1 = fmaf(c1[e], x, d1);
            d2 = fmaf(c2[e], x, d2);
        }
        #pragma unroll
        for (int off = 32; off; off >>= 1) {
            d1 += __shfl_down(d1, off);
            d2 += __shfl_down(d2, off);
        }
        d1 = __shfl(d1, 0);
        d2 = __shfl(d2, 0);
        const float s1 = esq[k1] - 2.f * d1;
        const float s2 = esq[k2] - 2.f * d2;
        if (s2 < s1 || (s2 == s1 && k2 < k1)) choice = (unsigned)k2;
    }

    // gather row + loss partial (3 float4 per lane)
    const float* crow = cb + (size_t)choice * D_DIM;
    const float* trow = token + (size_t)t * D_DIM;
    float*       qrow = out_q + (size_t)t * D_DIM;
    float lsum = 0.f;
    #pragma unroll
    for (int u = 0; u < 3; ++u) {
        const int e = (u * 64 + lane) * 4;
        const float4 q = *(const float4*)(crow + e);
        const float4 x = *(const float4*)(trow + e);
        *(float4*)(qrow + e) = q;
        const float dx = q.x - x.x, dy = q.y - x.y, dz = q.z - x.z, dw = q.w - x.w;
        lsum += dx * dx + dy * dy + dz * dz + dw * dw;
    }
    if (!lane) out_idx[t] = (float)choice;

    #pragma unroll
    for (int off = 32; off; off >>= 1) lsum += __shfl_down(lsum, off);
    __shared__ float ws4[4];
    if (!lane) ws4[w] = lsum;
    __syncthreads();
    if (!threadIdx.x)
        atomicAdd(out_loss, (ws4[0] + ws4[1] + ws4[2] + ws4[3]) *
                            (1.0f / (float)((size_t)M_TOK * D_DIM)));
}

// ---------------------------------------------------------------------------
extern "C" void kernel_launch(void* const* d_in, const int* in_sizes, int n_in,
                              void* d_out, int out_size, void* d_ws, size_t ws_size,
                              hipStream_t stream) {
    const float* token = (const float*)d_in[0];
    const float* cb    = (const float*)d_in[1];

    float* out_q    = (float*)d_out;
    float* out_idx  = out_q + (size_t)M_TOK * D_DIM;
    float* out_loss = out_idx + M_TOK;

    // token planes live in the out_q region (exactly 50,331,648 B), which
    // vq_final fully overwrites afterwards.
    unsigned short* tok_hi = (unsigned short*)out_q;
    unsigned short* tok_lo = tok_hi + (size_t)M_TOK * D_DIM;

    char* ws = (char*)d_ws;
    unsigned short* cb_hi = (unsigned short*)(ws);                 // 3,145,728 B
    unsigned short* cb_lo = (unsigned short*)(ws + 3145728);       // 3,145,728 B
    float*          esq   = (float*)(ws + 6291456);                // 8,192 B
    float4*         top2  = (float4*)(ws + 6299648);               // 4,194,304 B

    hipMemsetAsync(out_loss, 0, sizeof(float), stream);

    vq_prep_cb<<<K_CB / 4, 256, 0, stream>>>(cb, cb_hi, cb_lo, esq);
    vq_prep_tok<<<3072, 256, 0, stream>>>(token, tok_hi, tok_lo);

    vq_dist_mfma<<<(M_TOK / BTOK) * KSPLIT, 256, 0, stream>>>(
        tok_hi, tok_lo, cb_hi, cb_lo, esq, top2);

    vq_final<<<M_TOK / 4, 256, 0, stream>>>(token, cb, esq, top2,
                                            out_q, out_idx, out_loss);
}

// Round 6
// 331.291 us; speedup vs baseline: 1.0506x; 1.0506x over previous
//
#include <hip/hip_runtime.h>

#define M_TOK 16384          // B*T
#define D_DIM 768
#define K_CB  2048

#define BTOK  64             // token tile
#define BCODE 512            // codes per block (token plane visited K/BCODE = 4x)
#define BK    32             // K chunk (one mfma k=32)
#define KSPLIT 4             // K_CB / BCODE
#define NT    (D_DIM / BK)   // 24 dc steps
#define NSLOT 16             // kslice(4) x wave-row(4)
#define EPS   0.25f          // rescore margin — round-3-proven value

typedef __attribute__((ext_vector_type(8))) short bf16x8;
typedef __attribute__((ext_vector_type(4))) float f32x4;

__device__ __forceinline__ unsigned short f2bf(float x) {   // RNE f32->bf16
    unsigned u = __float_as_uint(x);
    return (unsigned short)((u + 0x7fffu + ((u >> 16) & 1u)) >> 16);
}
__device__ __forceinline__ float bf2f(unsigned short h) {
    return __uint_as_float((unsigned)h << 16);
}

#define ASYNC16(gp, lp) __builtin_amdgcn_global_load_lds( \
    (const __attribute__((address_space(1))) void*)(gp),  \
    (__attribute__((address_space(3))) void*)(lp), 16, 0, 0)

// ---------------------------------------------------------------------------
// Fused prep: blocks 0..511 -> codebook hi/lo planes + esq (one wave/code);
//             blocks 512..767 -> token hi AND lo planes (grid-stride).
// ---------------------------------------------------------------------------
__global__ void vq_prep(const float* __restrict__ cb,
                        const float* __restrict__ tok,
                        unsigned short* __restrict__ cb_hi,
                        unsigned short* __restrict__ cb_lo,
                        float* __restrict__ esq,
                        unsigned short* __restrict__ tok_hi,
                        unsigned short* __restrict__ tok_lo) {
    const int bid = blockIdx.x;
    if (bid < 512) {
        const int w = threadIdx.x >> 6, lane = threadIdx.x & 63;
        const int k = bid * 4 + w;
        const float* row = cb + (size_t)k * D_DIM;
        unsigned short* hk = cb_hi + (size_t)k * D_DIM;
        unsigned short* lk = cb_lo + (size_t)k * D_DIM;
        float s = 0.f;
        for (int j = lane; j < D_DIM; j += 64) {
            float x = row[j];
            s = fmaf(x, x, s);
            unsigned short h = f2bf(x);
            hk[j] = h;
            lk[j] = f2bf(x - bf2f(h));
        }
        #pragma unroll
        for (int off = 32; off; off >>= 1) s += __shfl_down(s, off);
        if (!lane) esq[k] = s;
    } else {
        const int N8 = (M_TOK * D_DIM) / 8;
        const int stride = 256 * 256;
        for (int i = (bid - 512) * 256 + threadIdx.x; i < N8; i += stride) {
            const float4 a = *(const float4*)(tok + (size_t)i * 8);
            const float4 b = *(const float4*)(tok + (size_t)i * 8 + 4);
            const float v[8] = {a.x, a.y, a.z, a.w, b.x, b.y, b.z, b.w};
            unsigned hh[8], ll[8];
            #pragma unroll
            for (int j = 0; j < 8; ++j) {
                const unsigned short h = f2bf(v[j]);
                hh[j] = h;
                ll[j] = f2bf(v[j] - bf2f(h));
            }
            uint4 ph, pl;
            ph.x = hh[0] | (hh[1] << 16);  ph.y = hh[2] | (hh[3] << 16);
            ph.z = hh[4] | (hh[5] << 16);  ph.w = hh[6] | (hh[7] << 16);
            pl.x = ll[0] | (ll[1] << 16);  pl.y = ll[2] | (ll[3] << 16);
            pl.z = ll[4] | (ll[5] << 16);  pl.w = ll[6] | (ll[7] << 16);
            *(uint4*)(tok_hi + (size_t)i * 8) = ph;
            *(uint4*)(tok_lo + (size_t)i * 8) = pl;
        }
    }
}

// ---------------------------------------------------------------------------
// Distance kernel: 512 threads = 8 waves (4 code-rows x 2 token-cols).
// Per block: 64 tokens x 512 codes, full D, 3-pass MFMA (xh*eh + xh*el
// + xl*eh) — per-accumulator order identical to the round-3-proven kernel,
// so approx distances are bit-identical to round 3's. Single-buffered LDS
// (74 KB -> 2 blocks/CU; co-resident block hides barrier drain, m114).
// Plain __syncthreads() pair. XOR-swizzled LDS (granule g of row r holds
// global slot g^((r>>1)&3)) — conflict-free; swizzle applied on the GLOBAL
// source address (LDS dest lane-linear).
// ---------------------------------------------------------------------------
__launch_bounds__(512, 4)
__global__ void vq_dist(const unsigned short* __restrict__ tok_hi,
                        const unsigned short* __restrict__ tok_lo,
                        const unsigned short* __restrict__ cb_hi,
                        const unsigned short* __restrict__ cb_lo,
                        const float* __restrict__ esq,
                        float4* __restrict__ top2) {
    __shared__ unsigned short sAh[BCODE * BK];   // 32 KB
    __shared__ unsigned short sAl[BCODE * BK];   // 32 KB
    __shared__ unsigned short sBh[BTOK * BK];    // 4 KB
    __shared__ unsigned short sBl[BTOK * BK];    // 4 KB
    __shared__ float sE[BCODE];                  // 2 KB

    const int tid  = threadIdx.x;
    const int lane = tid & 63;
    const int w    = tid >> 6;

    // Bijective XCD map: xcd = bid&7; ksl per XCD-pair -> 1.5MB cb slice
    // L2-resident; txi spans token tiles.
    const int bid = blockIdx.x;
    const int xcd = bid & 7;
    const int m   = bid >> 3;                 // 0..127
    const int ksl = xcd >> 1;                 // 0..3
    const int txi = m | ((xcd & 1) << 7);     // 0..255
    const int tokBase = txi * BTOK;
    const int kBase   = ksl * BCODE;

    for (int j = tid; j < BCODE; j += 512) sE[j] = esq[kBase + j];

    // staging offsets: A 4 granules/plane/thread; B 1 granule/thread
    // (tid<256 -> hi plane, tid>=256 -> lo plane; wave-uniform select)
    int gOffA[4], ldsA[4];
    #pragma unroll
    for (int q = 0; q < 4; ++q) {
        const int G   = q * 512 + tid;
        const int row = G >> 2;
        const int sl  = (G & 3) ^ ((row >> 1) & 3);
        gOffA[q] = row * D_DIM + sl * 8;      // element offset in plane
        ldsA[q]  = G * 16;                    // byte offset in LDS (lane-linear)
    }
    const int gB   = tid & 255;               // granule id within a B plane
    const int rowB = gB >> 2;                 // 0..63
    const int slB  = (gB & 3) ^ ((rowB >> 1) & 3);
    const int gOffB = rowB * D_DIM + slB * 8;
    const int ldsB  = gB * 16;                // lane-linear within each wave

    const unsigned short* pAh = cb_hi + (size_t)kBase * D_DIM;
    const unsigned short* pAl = cb_lo + (size_t)kBase * D_DIM;
    const unsigned short* pBsel = ((tid < 256) ? tok_hi : tok_lo)
                                  + (size_t)tokBase * D_DIM;
    char* sBsel = (tid < 256) ? (char*)sBh : (char*)sBl;

    // frag read byte-offsets (same XOR on the read side)
    const int h  = lane >> 4;
    const int lm = lane & 15;
    const int wr = w >> 1;             // 0..3 code-row group (128 codes each)
    const int wc = wr * 128;
    const int wt = (w & 1) * 32;       // token col group (32 tokens each)
    int offA[8], offB[2];
    #pragma unroll
    for (int i = 0; i < 8; ++i) {
        const int rA = wc + i * 16 + lm;
        offA[i] = rA * 64 + ((h ^ ((rA >> 1) & 3)) * 16);
    }
    #pragma unroll
    for (int j = 0; j < 2; ++j) {
        const int rB = wt + j * 16 + lm;
        offB[j] = rB * 64 + ((h ^ ((rB >> 1) & 3)) * 16);
    }

    f32x4 acc[8][2];
    #pragma unroll
    for (int i = 0; i < 8; ++i)
        #pragma unroll
        for (int j = 0; j < 2; ++j) acc[i][j] = (f32x4){0.f, 0.f, 0.f, 0.f};

    for (int t = 0; t < NT; ++t) {
        const int dco = t * BK;
        __syncthreads();   // all waves done reading LDS from step t-1
        #pragma unroll
        for (int q = 0; q < 4; ++q) {
            ASYNC16(pAh + gOffA[q] + dco, (char*)sAh + ldsA[q]);
            ASYNC16(pAl + gOffA[q] + dco, (char*)sAl + ldsA[q]);
        }
        ASYNC16(pBsel + gOffB + dco, sBsel + ldsB);
        __syncthreads();   // compiler drains vmcnt(0)+lgkmcnt(0) here

        bf16x8 bh[2], bl[2];
        #pragma unroll
        for (int j = 0; j < 2; ++j) {
            bh[j] = *(const bf16x8*)((const char*)sBh + offB[j]);
            bl[j] = *(const bf16x8*)((const char*)sBl + offB[j]);
        }
        // per-acc[i][j] MFMA order = (ah,bh), (ah,bl), (al,bh) — identical
        // fp32 sequence to the round-3-proven kernel => bit-identical dots.
        #pragma unroll
        for (int i = 0; i < 8; ++i) {
            const bf16x8 ah = *(const bf16x8*)((const char*)sAh + offA[i]);
            acc[i][0] = __builtin_amdgcn_mfma_f32_16x16x32_bf16(ah, bh[0], acc[i][0], 0, 0, 0);
            acc[i][1] = __builtin_amdgcn_mfma_f32_16x16x32_bf16(ah, bh[1], acc[i][1], 0, 0, 0);
            acc[i][0] = __builtin_amdgcn_mfma_f32_16x16x32_bf16(ah, bl[0], acc[i][0], 0, 0, 0);
            acc[i][1] = __builtin_amdgcn_mfma_f32_16x16x32_bf16(ah, bl[1], acc[i][1], 0, 0, 0);
            const bf16x8 al = *(const bf16x8*)((const char*)sAl + offA[i]);
            acc[i][0] = __builtin_amdgcn_mfma_f32_16x16x32_bf16(al, bh[0], acc[i][0], 0, 0, 0);
            acc[i][1] = __builtin_amdgcn_mfma_f32_16x16x32_bf16(al, bh[1], acc[i][1], 0, 0, 0);
        }
    }

    // epilogue: per token-frag j, top2 over this lane's 32 codes (ascending),
    // then cross-lane merge of the 4 k-groups, write slot.
    #pragma unroll
    for (int j = 0; j < 2; ++j) {
        float m1 = 3.4e38f, m2 = 3.4e38f;
        int   k1 = 0x7fffffff, k2 = 0x7fffffff;
        #pragma unroll
        for (int i = 0; i < 8; ++i)
            #pragma unroll
            for (int r = 0; r < 4; ++r) {
                const int cl = wc + i * 16 + (lane >> 4) * 4 + r;
                const float s = sE[cl] - 2.0f * acc[i][j][r];
                const int kg = kBase + cl;
                if (s < m1)      { m2 = m1; k2 = k1; m1 = s; k1 = kg; }
                else if (s < m2) { m2 = s; k2 = kg; }
            }
        #pragma unroll
        for (int off = 16; off <= 32; off <<= 1) {
            const float om1 = __shfl_xor(m1, off); const int ok1 = __shfl_xor(k1, off);
            const float om2 = __shfl_xor(m2, off); const int ok2 = __shfl_xor(k2, off);
            const bool aB = (m1 < om1) || (m1 == om1 && k1 < ok1);
            float n1m, n2m; int n1k, n2k;
            if (aB) {
                n1m = m1; n1k = k1;
                const bool c = (om1 < m2) || (om1 == m2 && ok1 < k2);
                n2m = c ? om1 : m2; n2k = c ? ok1 : k2;
            } else {
                n1m = om1; n1k = ok1;
                const bool c = (m1 < om2) || (m1 == om2 && k1 < ok2);
                n2m = c ? m1 : om2; n2k = c ? k1 : ok2;
            }
            m1 = n1m; k1 = n1k; m2 = n2m; k2 = n2k;
        }
        if (lane < 16) {
            const int tt = tokBase + wt + j * 16 + lane;
            top2[(size_t)tt * NSLOT + (ksl * 4 + wr)] =
                make_float4(m1, __int_as_float(k1), m2, __int_as_float(k2));
        }
    }
}

// ---------------------------------------------------------------------------
// Final (fused rescore+gather): one wave per token. Merge 16 top2 slots,
// exact fp32 rescore when gap <= EPS, gather row, indices, commit loss.
// ---------------------------------------------------------------------------
__global__ void vq_final(const float* __restrict__ token,
                         const float* __restrict__ cb,
                         const float* __restrict__ esq,
                         const float4* __restrict__ top2,
                         float* __restrict__ out_q,
                         float* __restrict__ out_idx,
                         float* __restrict__ out_loss) {
    const int w = threadIdx.x >> 6, lane = threadIdx.x & 63;
    const int t = blockIdx.x * 4 + w;

    // lane-parallel slot load (each slot 4x duplicated), butterfly merge
    const float4 sv = top2[(size_t)t * NSLOT + (lane & 15)];
    float m1 = sv.x, m2 = sv.z;
    int   k1 = __float_as_int(sv.y), k2 = __float_as_int(sv.w);
    #pragma unroll
    for (int off = 1; off <= 8; off <<= 1) {
        const float om1 = __shfl_xor(m1, off); const int ok1 = __shfl_xor(k1, off);
        const float om2 = __shfl_xor(m2, off); const int ok2 = __shfl_xor(k2, off);
        const bool aB = (m1 < om1) || (m1 == om1 && k1 < ok1);
        float n1m, n2m; int n1k, n2k;
        if (aB) {
            n1m = m1; n1k = k1;
            const bool c = (om1 < m2) || (om1 == m2 && ok1 < k2);
            n2m = c ? om1 : m2; n2k = c ? ok1 : k2;
        } else {
            n1m = om1; n1k = ok1;
            const bool c = (m1 < om2) || (m1 == om2 && k1 < ok2);
            n2m = c ? m1 : om2; n2k = c ? k1 : ok2;
        }
        m1 = n1m; k1 = n1k; m2 = n2m; k2 = n2k;
    }

    unsigned choice = (unsigned)k1;
    if (!(m2 - m1 > EPS)) {
        // exact fp32 rescore of both candidates (wave-uniform branch)
        const float* tr = token + (size_t)t * D_DIM;
        const float* c1 = cb + (size_t)k1 * D_DIM;
        const float* c2 = cb + (size_t)k2 * D_DIM;
        float d1 = 0.f, d2 = 0.f;
        for (int e = lane; e < D_DIM; e += 64) {
            const float x = tr[e];
            d1 = fmaf(c1[e], x, d1);
            d2 = fmaf(c2[e], x, d2);
        }
        #pragma unroll
        for (int off = 32; off; off >>= 1) {
            d1 += __shfl_down(d1, off);
            d2 += __shfl_down(d2, off);
        }
        d1 = __shfl(d1, 0);
        d2 = __shfl(d2, 0);
        const float s1 = esq[k1] - 2.f * d1;
        const float s2 = esq[k2] - 2.f * d2;
        if (s2 < s1 || (s2 == s1 && k2 < k1)) choice = (unsigned)k2;
    }

    // gather row + loss partial (3 float4 per lane)
    const float* crow = cb + (size_t)choice * D_DIM;
    const float* trow = token + (size_t)t * D_DIM;
    float*       qrow = out_q + (size_t)t * D_DIM;
    float lsum = 0.f;
    #pragma unroll
    for (int u = 0; u < 3; ++u) {
        const int e = (u * 64 + lane) * 4;
        const float4 q = *(const float4*)(crow + e);
        const float4 x = *(const float4*)(trow + e);
        *(float4*)(qrow + e) = q;
        const float dx = q.x - x.x, dy = q.y - x.y, dz = q.z - x.z, dw = q.w - x.w;
        lsum += dx * dx + dy * dy + dz * dz + dw * dw;
    }
    if (!lane) out_idx[t] = (float)choice;

    #pragma unroll
    for (int off = 32; off; off >>= 1) lsum += __shfl_down(lsum, off);
    __shared__ float ws4[4];
    if (!lane) ws4[w] = lsum;
    __syncthreads();
    if (!threadIdx.x)
        atomicAdd(out_loss, (ws4[0] + ws4[1] + ws4[2] + ws4[3]) *
                            (1.0f / (float)((size_t)M_TOK * D_DIM)));
}

// ---------------------------------------------------------------------------
extern "C" void kernel_launch(void* const* d_in, const int* in_sizes, int n_in,
                              void* d_out, int out_size, void* d_ws, size_t ws_size,
                              hipStream_t stream) {
    const float* token = (const float*)d_in[0];
    const float* cb    = (const float*)d_in[1];

    float* out_q    = (float*)d_out;
    float* out_idx  = out_q + (size_t)M_TOK * D_DIM;
    float* out_loss = out_idx + M_TOK;

    // token hi+lo planes live in the out_q region (exactly 50,331,648 B),
    // which vq_final fully overwrites afterwards (round-3-proven pattern).
    unsigned short* tok_hi = (unsigned short*)out_q;
    unsigned short* tok_lo = tok_hi + (size_t)M_TOK * D_DIM;

    char* ws = (char*)d_ws;
    unsigned short* cb_hi = (unsigned short*)(ws);                 // 3,145,728 B
    unsigned short* cb_lo = (unsigned short*)(ws + 3145728);       // 3,145,728 B
    float*          esq   = (float*)(ws + 6291456);                // 8,192 B
    float4*         top2  = (float4*)(ws + 6299648);               // 4,194,304 B

    hipMemsetAsync(out_loss, 0, sizeof(float), stream);

    vq_prep<<<768, 256, 0, stream>>>(cb, token, cb_hi, cb_lo, esq,
                                     tok_hi, tok_lo);

    vq_dist<<<(M_TOK / BTOK) * KSPLIT, 512, 0, stream>>>(
        tok_hi, tok_lo, cb_hi, cb_lo, esq, top2);

    vq_final<<<M_TOK / 4, 256, 0, stream>>>(token, cb, esq, top2,
                                            out_q, out_idx, out_loss);
}

// Round 7
// 315.869 us; speedup vs baseline: 1.1019x; 1.0488x over previous
//
#include <hip/hip_runtime.h>

#define M_TOK 16384          // B*T
#define D_DIM 768
#define K_CB  2048

#define BTOK  256            // token tile
#define BCODE 256            // code tile
#define BK    32             // K chunk (one mfma k=32)
#define KSPLIT 8             // K_CB / BCODE
#define NT    (D_DIM / BK)   // 24 dc steps
#define NSLOT 8              // one slot per kslice (block-internal wr-merge)
#define EPS   0.25f          // rescore margin — round-3/6-proven value

typedef __attribute__((ext_vector_type(8))) short bf16x8;
typedef __attribute__((ext_vector_type(4))) float f32x4;

__device__ __forceinline__ unsigned short f2bf(float x) {   // RNE f32->bf16
    unsigned u = __float_as_uint(x);
    return (unsigned short)((u + 0x7fffu + ((u >> 16) & 1u)) >> 16);
}
__device__ __forceinline__ float bf2f(unsigned short h) {
    return __uint_as_float((unsigned)h << 16);
}

#define ASYNC16(gp, lp) __builtin_amdgcn_global_load_lds( \
    (const __attribute__((address_space(1))) void*)(gp),  \
    (__attribute__((address_space(3))) void*)(lp), 16, 0, 0)

// ---------------------------------------------------------------------------
// Fused prep: blocks 0..511 -> codebook hi/lo planes + esq (one wave/code);
//             blocks 512..767 -> token hi AND lo planes (grid-stride).
// Block 511 thread 0 also zeroes out_loss (replaces a memset dispatch).
// ---------------------------------------------------------------------------
__global__ void vq_prep(const float* __restrict__ cb,
                        const float* __restrict__ tok,
                        unsigned short* __restrict__ cb_hi,
                        unsigned short* __restrict__ cb_lo,
                        float* __restrict__ esq,
                        unsigned short* __restrict__ tok_hi,
                        unsigned short* __restrict__ tok_lo,
                        float* __restrict__ out_loss) {
    const int bid = blockIdx.x;
    if (bid < 512) {
        if (bid == 511 && threadIdx.x == 0) *out_loss = 0.f;
        const int w = threadIdx.x >> 6, lane = threadIdx.x & 63;
        const int k = bid * 4 + w;
        const float* row = cb + (size_t)k * D_DIM;
        unsigned short* hk = cb_hi + (size_t)k * D_DIM;
        unsigned short* lk = cb_lo + (size_t)k * D_DIM;
        float s = 0.f;
        for (int j = lane; j < D_DIM; j += 64) {
            float x = row[j];
            s = fmaf(x, x, s);
            unsigned short h = f2bf(x);
            hk[j] = h;
            lk[j] = f2bf(x - bf2f(h));
        }
        #pragma unroll
        for (int off = 32; off; off >>= 1) s += __shfl_down(s, off);
        if (!lane) esq[k] = s;
    } else {
        const int N8 = (M_TOK * D_DIM) / 8;
        const int stride = 256 * 256;
        for (int i = (bid - 512) * 256 + threadIdx.x; i < N8; i += stride) {
            const float4 a = *(const float4*)(tok + (size_t)i * 8);
            const float4 b = *(const float4*)(tok + (size_t)i * 8 + 4);
            const float v[8] = {a.x, a.y, a.z, a.w, b.x, b.y, b.z, b.w};
            unsigned hh[8], ll[8];
            #pragma unroll
            for (int j = 0; j < 8; ++j) {
                const unsigned short h = f2bf(v[j]);
                hh[j] = h;
                ll[j] = f2bf(v[j] - bf2f(h));
            }
            uint4 ph, pl;
            ph.x = hh[0] | (hh[1] << 16);  ph.y = hh[2] | (hh[3] << 16);
            ph.z = hh[4] | (hh[5] << 16);  ph.w = hh[6] | (hh[7] << 16);
            pl.x = ll[0] | (ll[1] << 16);  pl.y = ll[2] | (ll[3] << 16);
            pl.z = ll[4] | (ll[5] << 16);  pl.w = ll[6] | (ll[7] << 16);
            *(uint4*)(tok_hi + (size_t)i * 8) = ph;
            *(uint4*)(tok_lo + (size_t)i * 8) = pl;
        }
    }
}

// ---------------------------------------------------------------------------
// Distance kernel: 512 threads = 8 waves; wave = 64 codes x 128 tokens
// (wr = w&3 code group, wt = w>>2 token group). Per block: 256 codes x
// 256 tokens, full D, 3-pass MFMA (xh*eh + xh*el + xl*eh) — per-acc order
// and ascending-K identical to r6 => bit-identical approx distances.
// Double-buffered LDS (128 KB, 1 block/CU). T3-minimum 2-phase schedule:
// STAGE(next); COMPUTE(cur); __syncthreads() — next-step loads in flight
// under current MFMA; the barrier's compiler-inserted vmcnt(0) drains them.
// XOR-swizzled LDS (granule g of row r at g^((r>>1)&3)) — conflict-free;
// swizzle on the GLOBAL source address (LDS dest lane-linear).
// ---------------------------------------------------------------------------
__launch_bounds__(512, 2)
__global__ void vq_dist(const unsigned short* __restrict__ tok_hi,
                        const unsigned short* __restrict__ tok_lo,
                        const unsigned short* __restrict__ cb_hi,
                        const unsigned short* __restrict__ cb_lo,
                        const float* __restrict__ esq,
                        float4* __restrict__ top2) {
    __shared__ __align__(16) unsigned short sAh[2][BCODE * BK];   // 2 x 16 KB
    __shared__ __align__(16) unsigned short sAl[2][BCODE * BK];   // 2 x 16 KB
    __shared__ __align__(16) unsigned short sBh[2][BTOK * BK];    // 2 x 16 KB
    __shared__ __align__(16) unsigned short sBl[2][BTOK * BK];    // 2 x 16 KB

    const int tid  = threadIdx.x;
    const int lane = tid & 63;
    const int w    = tid >> 6;

    // XCD map: xcd = bid&7 owns one kslice -> 786KB cb slice stays L2-hot
    // across both grid rounds; token tiles stream.
    const int bid = blockIdx.x;
    const int ksl = bid & 7;
    const int txi = bid >> 3;                 // 0..63
    const int tokBase = txi * BTOK;
    const int kBase   = ksl * BCODE;

    // staging offsets: 2 granules per plane per thread (1024 granules/plane)
    int gOff[2], gLds[2];
    #pragma unroll
    for (int q = 0; q < 2; ++q) {
        const int G   = q * 512 + tid;
        const int row = G >> 2;
        const int sl  = (G & 3) ^ ((row >> 1) & 3);
        gOff[q] = row * D_DIM + sl * 8;       // element offset in plane
        gLds[q] = G * 16;                     // byte offset in LDS (lane-linear)
    }

    const unsigned short* pAh = cb_hi + (size_t)kBase * D_DIM;
    const unsigned short* pAl = cb_lo + (size_t)kBase * D_DIM;
    const unsigned short* pBh = tok_hi + (size_t)tokBase * D_DIM;
    const unsigned short* pBl = tok_lo + (size_t)tokBase * D_DIM;

    // frag read byte-offsets (same XOR on the read side)
    const int h  = lane >> 4;
    const int lm = lane & 15;
    const int wr = w & 3;              // code group (64 codes)
    const int wc = wr * 64;
    const int wt = w >> 2;             // token group (128 tokens)
    const int wtb = wt * 128;
    int offA[4], offB[8];
    #pragma unroll
    for (int i = 0; i < 4; ++i) {
        const int rA = wc + i * 16 + lm;
        offA[i] = rA * 64 + ((h ^ ((rA >> 1) & 3)) * 16);
    }
    #pragma unroll
    for (int j = 0; j < 8; ++j) {
        const int rB = wtb + j * 16 + lm;
        offB[j] = rB * 64 + ((h ^ ((rB >> 1) & 3)) * 16);
    }

    f32x4 acc[4][8];
    #pragma unroll
    for (int i = 0; i < 4; ++i)
        #pragma unroll
        for (int j = 0; j < 8; ++j) acc[i][j] = (f32x4){0.f, 0.f, 0.f, 0.f};

#define STAGE(b, t) do {                                                    \
        const int dco = (t) * BK;                                           \
        _Pragma("unroll")                                                   \
        for (int q = 0; q < 2; ++q) {                                       \
            ASYNC16(pAh + gOff[q] + dco, (char*)&sAh[b][0] + gLds[q]);      \
            ASYNC16(pAl + gOff[q] + dco, (char*)&sAl[b][0] + gLds[q]);      \
            ASYNC16(pBh + gOff[q] + dco, (char*)&sBh[b][0] + gLds[q]);      \
            ASYNC16(pBl + gOff[q] + dco, (char*)&sBl[b][0] + gLds[q]);      \
        }                                                                   \
    } while (0)

#define COMPUTE(b) do {                                                     \
        bf16x8 ah[4], al[4];                                                \
        _Pragma("unroll")                                                   \
        for (int i = 0; i < 4; ++i) {                                       \
            ah[i] = *(const bf16x8*)((const char*)&sAh[b][0] + offA[i]);    \
            al[i] = *(const bf16x8*)((const char*)&sAl[b][0] + offA[i]);    \
        }                                                                   \
        _Pragma("unroll")                                                   \
        for (int j = 0; j < 8; ++j) {                                       \
            const bf16x8 bh = *(const bf16x8*)((const char*)&sBh[b][0] + offB[j]); \
            const bf16x8 bl = *(const bf16x8*)((const char*)&sBl[b][0] + offB[j]); \
            _Pragma("unroll")                                               \
            for (int i = 0; i < 4; ++i) {                                   \
                acc[i][j] = __builtin_amdgcn_mfma_f32_16x16x32_bf16(ah[i], bh, acc[i][j], 0, 0, 0); \
                acc[i][j] = __builtin_amdgcn_mfma_f32_16x16x32_bf16(ah[i], bl, acc[i][j], 0, 0, 0); \
                acc[i][j] = __builtin_amdgcn_mfma_f32_16x16x32_bf16(al[i], bh, acc[i][j], 0, 0, 0); \
            }                                                               \
        }                                                                   \
    } while (0)

    STAGE(0, 0);
    __syncthreads();                       // drain stage 0
    for (int t = 0; t < NT - 1; ++t) {
        STAGE((t + 1) & 1, t + 1);         // next-step loads fly under MFMA
        COMPUTE(t & 1);
        __syncthreads();                   // vmcnt(0)+lgkm drain + sync
    }
    COMPUTE((NT - 1) & 1);

#undef STAGE
#undef COMPUTE

    // esq for this lane's 16 codes (L1-hot, 8 KB table)
    float es[4][4];
    #pragma unroll
    for (int i = 0; i < 4; ++i)
        #pragma unroll
        for (int r = 0; r < 4; ++r)
            es[i][r] = esq[kBase + wc + i * 16 + (lane >> 4) * 4 + r];

    // per token-frag j: top2 over this lane's 16 codes (ascending), then
    // cross-lane merge of the 4 k-groups; lanes<16 write to LDS scratch.
    // Scratch aliases buffer 0 of sAh/sAl (last read finished 2 barriers ago).
    float4* scr = (float4*)&sAh[0][0];     // [256 tokens][4 wr] = 16 KB
    #pragma unroll
    for (int j = 0; j < 8; ++j) {
        float m1 = 3.4e38f, m2 = 3.4e38f;
        int   k1 = 0x7fffffff, k2 = 0x7fffffff;
        #pragma unroll
        for (int i = 0; i < 4; ++i)
            #pragma unroll
            for (int r = 0; r < 4; ++r) {
                const float s = es[i][r] - 2.0f * acc[i][j][r];
                const int kg = kBase + wc + i * 16 + (lane >> 4) * 4 + r;
                if (s < m1)      { m2 = m1; k2 = k1; m1 = s; k1 = kg; }
                else if (s < m2) { m2 = s; k2 = kg; }
            }
        #pragma unroll
        for (int off = 16; off <= 32; off <<= 1) {
            const float om1 = __shfl_xor(m1, off); const int ok1 = __shfl_xor(k1, off);
            const float om2 = __shfl_xor(m2, off); const int ok2 = __shfl_xor(k2, off);
            const bool aB = (m1 < om1) || (m1 == om1 && k1 < ok1);
            float n1m, n2m; int n1k, n2k;
            if (aB) {
                n1m = m1; n1k = k1;
                const bool c = (om1 < m2) || (om1 == m2 && ok1 < k2);
                n2m = c ? om1 : m2; n2k = c ? ok1 : k2;
            } else {
                n1m = om1; n1k = ok1;
                const bool c = (m1 < om2) || (m1 == om2 && k1 < ok2);
                n2m = c ? m1 : om2; n2k = c ? k1 : ok2;
            }
            m1 = n1m; k1 = n1k; m2 = n2m; k2 = n2k;
        }
        if (lane < 16)
            scr[(wtb + j * 16 + lane) * 4 + wr] =
                make_float4(m1, __int_as_float(k1), m2, __int_as_float(k2));
    }
    __syncthreads();

    // block-level merge of the 4 wr-groups (ascending wr = ascending k),
    // one thread per token; write the block's single slot (ksl).
    if (tid < BTOK) {
        const float4 c0 = scr[tid * 4 + 0];
        float m1 = c0.x, m2 = c0.z;
        int   k1 = __float_as_int(c0.y), k2 = __float_as_int(c0.w);
        #pragma unroll
        for (int s = 1; s < 4; ++s) {
            const float4 sv = scr[tid * 4 + s];
            const float om1 = sv.x, om2 = sv.z;
            const int ok1 = __float_as_int(sv.y), ok2 = __float_as_int(sv.w);
            const bool aB = (m1 < om1) || (m1 == om1 && k1 < ok1);
            float n1m, n2m; int n1k, n2k;
            if (aB) {
                n1m = m1; n1k = k1;
                const bool c = (om1 < m2) || (om1 == m2 && ok1 < k2);
                n2m = c ? om1 : m2; n2k = c ? ok1 : k2;
            } else {
                n1m = om1; n1k = ok1;
                const bool c = (m1 < om2) || (m1 == om2 && k1 < ok2);
                n2m = c ? m1 : om2; n2k = c ? k1 : ok2;
            }
            m1 = n1m; k1 = n1k; m2 = n2m; k2 = n2k;
        }
        top2[(size_t)(tokBase + tid) * NSLOT + ksl] =
            make_float4(m1, __int_as_float(k1), m2, __int_as_float(k2));
    }
}

// ---------------------------------------------------------------------------
// Final (fused rescore+gather): one wave per token. Merge 8 top2 slots,
// exact fp32 rescore when gap <= EPS, gather row, indices, commit loss.
// ---------------------------------------------------------------------------
__global__ void vq_final(const float* __restrict__ token,
                         const float* __restrict__ cb,
                         const float* __restrict__ esq,
                         const float4* __restrict__ top2,
                         float* __restrict__ out_q,
                         float* __restrict__ out_idx,
                         float* __restrict__ out_loss) {
    const int w = threadIdx.x >> 6, lane = threadIdx.x & 63;
    const int t = blockIdx.x * 4 + w;

    // lane-parallel slot load (each slot 8x duplicated), butterfly merge
    const float4 sv = top2[(size_t)t * NSLOT + (lane & 7)];
    float m1 = sv.x, m2 = sv.z;
    int   k1 = __float_as_int(sv.y), k2 = __float_as_int(sv.w);
    #pragma unroll
    for (int off = 1; off <= 4; off <<= 1) {
        const float om1 = __shfl_xor(m1, off); const int ok1 = __shfl_xor(k1, off);
        const float om2 = __shfl_xor(m2, off); const int ok2 = __shfl_xor(k2, off);
        const bool aB = (m1 < om1) || (m1 == om1 && k1 < ok1);
        float n1m, n2m; int n1k, n2k;
        if (aB) {
            n1m = m1; n1k = k1;
            const bool c = (om1 < m2) || (om1 == m2 && ok1 < k2);
            n2m = c ? om1 : m2; n2k = c ? ok1 : k2;
        } else {
            n1m = om1; n1k = ok1;
            const bool c = (m1 < om2) || (m1 == om2 && k1 < ok2);
            n2m = c ? m1 : om2; n2k = c ? k1 : ok2;
        }
        m1 = n1m; k1 = n1k; m2 = n2m; k2 = n2k;
    }

    unsigned choice = (unsigned)k1;
    if (!(m2 - m1 > EPS)) {
        // exact fp32 rescore of both candidates (wave-uniform branch)
        const float* tr = token + (size_t)t * D_DIM;
        const float* c1 = cb + (size_t)k1 * D_DIM;
        const float* c2 = cb + (size_t)k2 * D_DIM;
        float d1 = 0.f, d2 = 0.f;
        for (int e = lane; e < D_DIM; e += 64) {
            const float x = tr[e];
            d1 = fmaf(c1[e], x, d1);
            d2 = fmaf(c2[e], x, d2);
        }
        #pragma unroll
        for (int off = 32; off; off >>= 1) {
            d1 += __shfl_down(d1, off);
            d2 += __shfl_down(d2, off);
        }
        d1 = __shfl(d1, 0);
        d2 = __shfl(d2, 0);
        const float s1 = esq[k1] - 2.f * d1;
        const float s2 = esq[k2] - 2.f * d2;
        if (s2 < s1 || (s2 == s1 && k2 < k1)) choice = (unsigned)k2;
    }

    // gather row + loss partial (3 float4 per lane)
    const float* crow = cb + (size_t)choice * D_DIM;
    const float* trow = token + (size_t)t * D_DIM;
    float*       qrow = out_q + (size_t)t * D_DIM;
    float lsum = 0.f;
    #pragma unroll
    for (int u = 0; u < 3; ++u) {
        const int e = (u * 64 + lane) * 4;
        const float4 q = *(const float4*)(crow + e);
        const float4 x = *(const float4*)(trow + e);
        *(float4*)(qrow + e) = q;
        const float dx = q.x - x.x, dy = q.y - x.y, dz = q.z - x.z, dw = q.w - x.w;
        lsum += dx * dx + dy * dy + dz * dz + dw * dw;
    }
    if (!lane) out_idx[t] = (float)choice;

    #pragma unroll
    for (int off = 32; off; off >>= 1) lsum += __shfl_down(lsum, off);
    __shared__ float ws4[4];
    if (!lane) ws4[w] = lsum;
    __syncthreads();
    if (!threadIdx.x)
        atomicAdd(out_loss, (ws4[0] + ws4[1] + ws4[2] + ws4[3]) *
                            (1.0f / (float)((size_t)M_TOK * D_DIM)));
}

// ---------------------------------------------------------------------------
extern "C" void kernel_launch(void* const* d_in, const int* in_sizes, int n_in,
                              void* d_out, int out_size, void* d_ws, size_t ws_size,
                              hipStream_t stream) {
    const float* token = (const float*)d_in[0];
    const float* cb    = (const float*)d_in[1];

    float* out_q    = (float*)d_out;
    float* out_idx  = out_q + (size_t)M_TOK * D_DIM;
    float* out_loss = out_idx + M_TOK;

    // token hi+lo planes live in the out_q region (exactly 50,331,648 B),
    // which vq_final fully overwrites afterwards (round-3/6-proven pattern).
    unsigned short* tok_hi = (unsigned short*)out_q;
    unsigned short* tok_lo = tok_hi + (size_t)M_TOK * D_DIM;

    char* ws = (char*)d_ws;
    unsigned short* cb_hi = (unsigned short*)(ws);                 // 3,145,728 B
    unsigned short* cb_lo = (unsigned short*)(ws + 3145728);       // 3,145,728 B
    float*          esq   = (float*)(ws + 6291456);                // 8,192 B
    float4*         top2  = (float4*)(ws + 6299648);               // 2,097,152 B

    vq_prep<<<768, 256, 0, stream>>>(cb, token, cb_hi, cb_lo, esq,
                                     tok_hi, tok_lo, out_loss);

    vq_dist<<<(M_TOK / BTOK) * KSPLIT, 512, 0, stream>>>(
        tok_hi, tok_lo, cb_hi, cb_lo, esq, top2);

    vq_final<<<M_TOK / 4, 256, 0, stream>>>(token, cb, esq, top2,
                                            out_q, out_idx, out_loss);
}